// Round 17
// baseline (251.809 us; speedup 1.0000x reference)
//
#include <hip/hip_runtime.h>
#include <hip/hip_fp16.h>

#define HID 32
#define BN 131         // nodes per bucket -> NB = ceil(100000/131) = 764
#define NBPAD 768      // padded bucket arrays (3 per thread in binscatter scan)
#define BSTRIDE 4608   // per-bucket edge capacity: mean 4194 +6.4 sigma
#define CHUNK 4096     // edges per binscatter chunk

__device__ __forceinline__ float lrelu(float x) { return x > 0.0f ? x : 0.2f * x; }

// ---------------- shared building blocks ----------------

struct BinSM {
    int stage[CHUNK];                 // 16 KB
    unsigned short sbid[CHUNK];       // 8 KB
    int lhist[NBPAD], lexcl[NBPAD], lbase[NBPAD], lcur[NBPAD];  // 12 KB
    int arr[256];                     // 1 KB
};
struct AggSM {
    int   lcsr[BSTRIDE];              // 18 KB
    float lexp[BSTRIDE];              // 18 KB
    int   lhist[256], lscan[256], lcur[256];  // 3 KB
    float adT[BN];                    // 0.5 KB
};
union FusedSM { BinSM bin; AggSM agg; };      // ~40.5 KB

// binscatter for one chunk, templated block size. LDS-staged sort by bucket
// so global writes are coalesced runs (R7/R12-proven). Scan runs on t<256.
template<int BLK>
__device__ __forceinline__ void binscatter_chunk(BinSM& S, int base,
        const int* __restrict__ src, const int* __restrict__ dst,
        int* __restrict__ cursor, unsigned int* __restrict__ packed,
        int NBr, int E)
{
    int t = threadIdx.x;
    for (int i = t; i < NBPAD; i += BLK) { S.lhist[i] = 0; S.lcur[i] = 0; }
    __syncthreads();
    int cnt = E - base; if (cnt > CHUNK) cnt = CHUNK;
    for (int i = t; i < cnt; i += BLK)
        atomicAdd(&S.lhist[dst[base + i] / BN], 1);
    __syncthreads();
    int b0 = 3 * t;
    int c0 = 0, c1 = 0, c2 = 0, s = 0;
    if (t < 256) {
        c0 = S.lhist[b0]; c1 = S.lhist[b0 + 1]; c2 = S.lhist[b0 + 2];
        s = c0 + c1 + c2;
        S.arr[t] = s;
    }
    __syncthreads();
    for (int o = 1; o < 256; o <<= 1) {
        int v = (t < 256 && t >= o) ? S.arr[t - o] : 0;
        __syncthreads();
        if (t < 256) S.arr[t] += v;
        __syncthreads();
    }
    if (t < 256) {
        int ex = S.arr[t] - s;
        int e0 = ex, e1 = ex + c0, e2 = ex + c0 + c1;
        S.lexcl[b0] = e0; S.lexcl[b0 + 1] = e1; S.lexcl[b0 + 2] = e2;
        for (int i = 0; i < c0; ++i) S.sbid[e0 + i] = (unsigned short)b0;
        for (int i = 0; i < c1; ++i) S.sbid[e1 + i] = (unsigned short)(b0 + 1);
        for (int i = 0; i < c2; ++i) S.sbid[e2 + i] = (unsigned short)(b0 + 2);
    }
    for (int b = t; b < NBr; b += BLK)
        if (S.lhist[b]) S.lbase[b] = b * BSTRIDE + atomicAdd(&cursor[b], S.lhist[b]);
    __syncthreads();
    for (int i = t; i < cnt; i += BLK) {
        int d = dst[base + i];
        int sv = src[base + i];
        int b = d / BN;
        int dl = d - b * BN;
        int idx = S.lexcl[b] + atomicAdd(&S.lcur[b], 1);
        S.stage[idx] = (int)((unsigned)sv | ((unsigned)dl << 17));
    }
    __syncthreads();
    for (int i = t; i < cnt; i += BLK) {
        int b = S.sbid[i];
        int gpos = S.lbase[b] + (i - S.lexcl[b]);
        if (gpos < (b + 1) * BSTRIDE)
            packed[gpos] = (unsigned)S.stage[i];
    }
}

// in-block CSR+exp build (R12-proven), templated on block size
template<int BLK>
__device__ __forceinline__ void build_csr_exp(int* lcsr, float* lexp, float* adT,
        int* lhist, int* lscan, int* lcur,
        const unsigned int* __restrict__ pk, int cnt,
        const float* __restrict__ a_s, const float* __restrict__ a_d,
        int nodeBase, int N)
{
    int t = threadIdx.x;
    if (t < 256) { lhist[t] = 0; lcur[t] = 0; }
    if (t < BN) { int n = nodeBase + t; adT[t] = (n < N) ? a_d[n] : 0.0f; }
    __syncthreads();
    for (int i = t; i < cnt; i += BLK)
        atomicAdd(&lhist[(pk[i] >> 17) & 255], 1);
    __syncthreads();
    if (t < 256) lscan[t] = lhist[t];
    __syncthreads();
    for (int o = 1; o < 256; o <<= 1) {
        int v = (t < 256 && t >= o) ? lscan[t - o] : 0;
        __syncthreads();
        if (t < 256) lscan[t] += v;
        __syncthreads();
    }
    for (int i = t; i < cnt; i += BLK) {
        unsigned p = pk[i];
        int dl = (p >> 17) & 255;
        int sv = (int)(p & 0x1FFFF);
        float e = __expf(lrelu(a_s[sv] + adT[dl]));
        int pos = atomicAdd(&lcur[dl], 1);
        int idx = (lscan[dl] - lhist[dl]) + pos;
        lcsr[idx] = sv;
        lexp[idx] = e;
    }
    __syncthreads();
}

// R12's agg inner loop verbatim: 16 lanes/node, den in-loop, unroll x8.
__device__ __forceinline__ void agg_node(const __half* __restrict__ hh,
                                         float ex_self, const float* __restrict__ b,
                                         int n, int f,
                                         const int* lcsr, const float* lexp,
                                         int off, int dg, float& vx, float& vy)
{
    float den = ex_self;
    float2 hs = __half22float2(*(const __half2*)(hh + (size_t)n * HID + 2 * f));
    float accx = ex_self * hs.x;
    float accy = ex_self * hs.y;
    int j = 0;
    for (; j + 8 <= dg; j += 8) {
        int s0 = lcsr[off + j + 0], s1 = lcsr[off + j + 1];
        int s2 = lcsr[off + j + 2], s3 = lcsr[off + j + 3];
        int s4 = lcsr[off + j + 4], s5 = lcsr[off + j + 5];
        int s6 = lcsr[off + j + 6], s7 = lcsr[off + j + 7];
        float e0 = lexp[off + j + 0], e1 = lexp[off + j + 1];
        float e2 = lexp[off + j + 2], e3 = lexp[off + j + 3];
        float e4 = lexp[off + j + 4], e5 = lexp[off + j + 5];
        float e6 = lexp[off + j + 6], e7 = lexp[off + j + 7];
        __half2 p0 = *(const __half2*)(hh + (size_t)s0 * HID + 2 * f);
        __half2 p1 = *(const __half2*)(hh + (size_t)s1 * HID + 2 * f);
        __half2 p2 = *(const __half2*)(hh + (size_t)s2 * HID + 2 * f);
        __half2 p3 = *(const __half2*)(hh + (size_t)s3 * HID + 2 * f);
        __half2 p4 = *(const __half2*)(hh + (size_t)s4 * HID + 2 * f);
        __half2 p5 = *(const __half2*)(hh + (size_t)s5 * HID + 2 * f);
        __half2 p6 = *(const __half2*)(hh + (size_t)s6 * HID + 2 * f);
        __half2 p7 = *(const __half2*)(hh + (size_t)s7 * HID + 2 * f);
        float2 q0 = __half22float2(p0), q1 = __half22float2(p1);
        float2 q2 = __half22float2(p2), q3 = __half22float2(p3);
        float2 q4 = __half22float2(p4), q5 = __half22float2(p5);
        float2 q6 = __half22float2(p6), q7 = __half22float2(p7);
        den += ((e0 + e1) + (e2 + e3)) + ((e4 + e5) + (e6 + e7));
        accx = fmaf(e0, q0.x, accx); accy = fmaf(e0, q0.y, accy);
        accx = fmaf(e1, q1.x, accx); accy = fmaf(e1, q1.y, accy);
        accx = fmaf(e2, q2.x, accx); accy = fmaf(e2, q2.y, accy);
        accx = fmaf(e3, q3.x, accx); accy = fmaf(e3, q3.y, accy);
        accx = fmaf(e4, q4.x, accx); accy = fmaf(e4, q4.y, accy);
        accx = fmaf(e5, q5.x, accx); accy = fmaf(e5, q5.y, accy);
        accx = fmaf(e6, q6.x, accx); accy = fmaf(e6, q6.y, accy);
        accx = fmaf(e7, q7.x, accx); accy = fmaf(e7, q7.y, accy);
    }
    for (; j < dg; ++j) {
        int s0 = lcsr[off + j];
        float e0 = lexp[off + j];
        float2 q0 = __half22float2(*(const __half2*)(hh + (size_t)s0 * HID + 2 * f));
        den += e0;
        accx = fmaf(e0, q0.x, accx);
        accy = fmaf(e0, q0.y, accy);
    }
    float inv = 1.0f / (den + 1e-16f);
    vx = fmaxf(accx * inv + b[2 * f], 0.0f);
    vy = fmaxf(accy * inv + b[2 * f + 1], 0.0f);
}

// layer-1 epilogue: W2 transform + layer-2 attention halves (width-16)
__device__ __forceinline__ void epi_mid(int n, int f, float vx, float vy,
        const float* __restrict__ W2, const float* __restrict__ as2w,
        const float* __restrict__ ad2w,
        __half* __restrict__ hh_out, float* __restrict__ as_out,
        float* __restrict__ ad_out)
{
    float hx = 0.0f, hy = 0.0f;
    #pragma unroll
    for (int k = 0; k < 16; ++k) {
        float va = __shfl(vx, k, 16);
        float vb = __shfl(vy, k, 16);
        float2 w0 = *(const float2*)(W2 + (2 * k) * HID + 2 * f);
        float2 w1 = *(const float2*)(W2 + (2 * k + 1) * HID + 2 * f);
        hx = fmaf(va, w0.x, hx); hy = fmaf(va, w0.y, hy);
        hx = fmaf(vb, w1.x, hx); hy = fmaf(vb, w1.y, hy);
    }
    *(__half2*)(hh_out + (size_t)n * HID + 2 * f) = __floats2half2_rn(hx, hy);
    float as = hx * as2w[2 * f] + hy * as2w[2 * f + 1];
    float ad = hx * ad2w[2 * f] + hy * ad2w[2 * f + 1];
    #pragma unroll
    for (int m2 = 8; m2 >= 1; m2 >>= 1) {
        as += __shfl_xor(as, m2, 16);
        ad += __shfl_xor(ad, m2, 16);
    }
    if (f == 0) { as_out[n] = as; ad_out[n] = ad; }
}

// software grid barrier: monotonic counter, device-scope; requires all blocks
// resident (checked on host via occupancy query before choosing this path).
__device__ __forceinline__ void grid_bar(int* bar, int target)
{
    __syncthreads();
    if (threadIdx.x == 0) {
        __threadfence();
        __hip_atomic_fetch_add(bar, 1, __ATOMIC_RELEASE, __HIP_MEMORY_SCOPE_AGENT);
        while (__hip_atomic_load(bar, __ATOMIC_ACQUIRE, __HIP_MEMORY_SCOPE_AGENT) < target)
            __builtin_amdgcn_s_sleep(8);
        __threadfence();
    }
    __syncthreads();
}

__global__ void k_zero_bar(int* __restrict__ bar)
{
    if (threadIdx.x < 4) bar[threadIdx.x] = 0;
}

// ---------------- fused persistent kernel (512 threads) ----------------
__global__ void __launch_bounds__(512) k_fused(
    const float* __restrict__ x, const int* __restrict__ src, const int* __restrict__ dst,
    const float* __restrict__ W1, const float* __restrict__ as1w,
    const float* __restrict__ ad1w, const float* __restrict__ b1,
    const float* __restrict__ W2, const float* __restrict__ as2w,
    const float* __restrict__ ad2w, const float* __restrict__ b2,
    const float* __restrict__ Wl, const float* __restrict__ bl,
    __half* __restrict__ h1h, __half* __restrict__ h2h,
    unsigned int* __restrict__ packed,
    float* __restrict__ a_s1, float* __restrict__ a_d1,
    float* __restrict__ a_s2, float* __restrict__ a_d2,
    int* __restrict__ cursor, int* __restrict__ bar,
    float* __restrict__ out, int N, int E, int NBr)
{
    __shared__ FusedSM sm;
    int t = threadIdx.x, bk = blockIdx.x;
    int nth = gridDim.x * 512, gtid = bk * 512 + t;

    // ---- phase 0: transform + cursor zero ----
    for (int i = gtid; i < NBPAD; i += nth) cursor[i] = 0;
    for (int idx = gtid; idx < N * HID; idx += nth) {
        int n = idx >> 5, f = idx & 31;
        float x0 = x[n * 3 + 0], x1 = x[n * 3 + 1], x2 = x[n * 3 + 2];
        float hv = x0 * W1[f] + x1 * W1[HID + f] + x2 * W1[2 * HID + f];
        h1h[(size_t)n * HID + f] = __float2half(hv);
        float as = hv * as1w[f];
        float ad = hv * ad1w[f];
        #pragma unroll
        for (int m = 16; m >= 1; m >>= 1) {
            as += __shfl_xor(as, m, 32);
            ad += __shfl_xor(ad, m, 32);
        }
        if (f == 0) { a_s1[n] = as; a_d1[n] = ad; }
    }
    grid_bar(bar, gridDim.x);

    // ---- phase 1: binscatter (grid-stride over chunks) ----
    int nch = (E + CHUNK - 1) / CHUNK;
    for (int c = bk; c < nch; c += gridDim.x) {
        binscatter_chunk<512>(sm.bin, c * CHUNK, src, dst, cursor, packed, NBr, E);
        __syncthreads();
    }
    grid_bar(bar, 2 * gridDim.x);

    // ---- phase 2: build + agg layer 1 ----
    int cnt = cursor[bk]; if (cnt > BSTRIDE) cnt = BSTRIDE;
    build_csr_exp<512>(sm.agg.lcsr, sm.agg.lexp, sm.agg.adT,
                       sm.agg.lhist, sm.agg.lscan, sm.agg.lcur,
                       packed + (size_t)bk * BSTRIDE, cnt, a_s1, a_d1, bk * BN, N);
    {
        int g = t >> 4, f = t & 15;      // 32 groups of 16 lanes
        for (int dl = g; dl < BN; dl += 32) {
            int n = bk * BN + dl;
            if (n >= N) continue;
            int off = sm.agg.lscan[dl] - sm.agg.lhist[dl];
            int dg = sm.agg.lhist[dl];
            float exs = __expf(lrelu(a_s1[n] + sm.agg.adT[dl]));
            float vx, vy;
            agg_node(h1h, exs, b1, n, f, sm.agg.lcsr, sm.agg.lexp, off, dg, vx, vy);
            epi_mid(n, f, vx, vy, W2, as2w, ad2w, h2h, a_s2, a_d2);
        }
    }
    grid_bar(bar, 3 * gridDim.x);

    // ---- phase 3: re-exp (CSR kept resident in LDS!) + agg layer 2 + head ----
    if (t < BN) { int n = bk * BN + t; sm.agg.adT[t] = (n < N) ? a_d2[n] : 0.0f; }
    __syncthreads();
    for (int i = t; i < cnt; i += 512) {
        int lo = 0, hi = BN - 1;            // owner node: smallest dl with lscan[dl] > i
        while (lo < hi) {
            int mid = (lo + hi) >> 1;
            if (sm.agg.lscan[mid] > i) hi = mid; else lo = mid + 1;
        }
        int sv = sm.agg.lcsr[i];
        sm.agg.lexp[i] = __expf(lrelu(a_s2[sv] + sm.agg.adT[lo]));
    }
    __syncthreads();
    {
        int g = t >> 4, f = t & 15;
        for (int dl = g; dl < BN; dl += 32) {
            int n = bk * BN + dl;
            if (n >= N) continue;
            int off = sm.agg.lscan[dl] - sm.agg.lhist[dl];
            int dg = sm.agg.lhist[dl];
            float exs = __expf(lrelu(a_s2[n] + sm.agg.adT[dl]));
            float vx, vy;
            agg_node(h2h, exs, b2, n, f, sm.agg.lcsr, sm.agg.lexp, off, dg, vx, vy);
            float y = vx * Wl[2 * f] + vy * Wl[2 * f + 1];
            #pragma unroll
            for (int m2 = 8; m2 >= 1; m2 >>= 1)
                y += __shfl_xor(y, m2, 16);
            if (f == 0) out[n] = y + bl[0];
        }
    }
}

// ---------------- fallback path (R12 structure, BSTRIDE 4608) ----------------

__global__ void k_transform1(const float* __restrict__ x,
                             const float* __restrict__ W1,
                             const float* __restrict__ att_src,
                             const float* __restrict__ att_dst,
                             __half* __restrict__ hh,
                             float* __restrict__ a_s,
                             float* __restrict__ a_d,
                             int* __restrict__ cursor, int N)
{
    int tid = blockIdx.x * blockDim.x + threadIdx.x;
    if (tid < NBPAD) cursor[tid] = 0;
    int n = tid >> 5, f = tid & 31;
    if (n >= N) return;
    float x0 = x[n * 3 + 0], x1 = x[n * 3 + 1], x2 = x[n * 3 + 2];
    float hv = x0 * W1[f] + x1 * W1[HID + f] + x2 * W1[2 * HID + f];
    hh[(size_t)n * HID + f] = __float2half(hv);
    float as = hv * att_src[f];
    float ad = hv * att_dst[f];
    #pragma unroll
    for (int m = 16; m >= 1; m >>= 1) {
        as += __shfl_xor(as, m, 32);
        ad += __shfl_xor(ad, m, 32);
    }
    if (f == 0) { a_s[n] = as; a_d[n] = ad; }
}

__global__ void __launch_bounds__(256) k_binscatter(const int* __restrict__ src,
        const int* __restrict__ dst, int* __restrict__ cursor,
        unsigned int* __restrict__ packed, int NBr, int E)
{
    __shared__ BinSM S;
    binscatter_chunk<256>(S, blockIdx.x * CHUNK, src, dst, cursor, packed, NBr, E);
}

__global__ void __launch_bounds__(512) k_agg_mid_f(const __half* __restrict__ hh,
        const float* __restrict__ a_s, const float* __restrict__ a_d,
        const int* __restrict__ cursor, const unsigned int* __restrict__ packed,
        const float* __restrict__ b1, const float* __restrict__ W2,
        const float* __restrict__ as2w, const float* __restrict__ ad2w,
        __half* __restrict__ hh_out, float* __restrict__ as_out,
        float* __restrict__ ad_out, int N)
{
    __shared__ AggSM S;
    int bk = blockIdx.x, t = threadIdx.x;
    int cnt = cursor[bk]; if (cnt > BSTRIDE) cnt = BSTRIDE;
    build_csr_exp<512>(S.lcsr, S.lexp, S.adT, S.lhist, S.lscan, S.lcur,
                       packed + (size_t)bk * BSTRIDE, cnt, a_s, a_d, bk * BN, N);
    int g = t >> 4, f = t & 15;
    for (int dl = g; dl < BN; dl += 32) {
        int n = bk * BN + dl;
        if (n >= N) continue;
        int off = S.lscan[dl] - S.lhist[dl];
        int dg = S.lhist[dl];
        float exs = __expf(lrelu(a_s[n] + S.adT[dl]));
        float vx, vy;
        agg_node(hh, exs, b1, n, f, S.lcsr, S.lexp, off, dg, vx, vy);
        epi_mid(n, f, vx, vy, W2, as2w, ad2w, hh_out, as_out, ad_out);
    }
}

__global__ void __launch_bounds__(512) k_agg_out_f(const __half* __restrict__ hh,
        const float* __restrict__ a_s, const float* __restrict__ a_d,
        const int* __restrict__ cursor, const unsigned int* __restrict__ packed,
        const float* __restrict__ b2, const float* __restrict__ Wl,
        const float* __restrict__ bl, float* __restrict__ out, int N)
{
    __shared__ AggSM S;
    int bk = blockIdx.x, t = threadIdx.x;
    int cnt = cursor[bk]; if (cnt > BSTRIDE) cnt = BSTRIDE;
    build_csr_exp<512>(S.lcsr, S.lexp, S.adT, S.lhist, S.lscan, S.lcur,
                       packed + (size_t)bk * BSTRIDE, cnt, a_s, a_d, bk * BN, N);
    int g = t >> 4, f = t & 15;
    for (int dl = g; dl < BN; dl += 32) {
        int n = bk * BN + dl;
        if (n >= N) continue;
        int off = S.lscan[dl] - S.lhist[dl];
        int dg = S.lhist[dl];
        float exs = __expf(lrelu(a_s[n] + S.adT[dl]));
        float vx, vy;
        agg_node(hh, exs, b2, n, f, S.lcsr, S.lexp, off, dg, vx, vy);
        float y = vx * Wl[2 * f] + vy * Wl[2 * f + 1];
        #pragma unroll
        for (int m2 = 8; m2 >= 1; m2 >>= 1)
            y += __shfl_xor(y, m2, 16);
        if (f == 0) out[n] = y + bl[0];
    }
}

extern "C" void kernel_launch(void* const* d_in, const int* in_sizes, int n_in,
                              void* d_out, int out_size, void* d_ws, size_t ws_size,
                              hipStream_t stream)
{
    const float* x        = (const float*)d_in[0];
    const int*   eidx     = (const int*)d_in[1];
    const float* W1       = (const float*)d_in[2];
    const float* att_src1 = (const float*)d_in[3];
    const float* att_dst1 = (const float*)d_in[4];
    const float* b1       = (const float*)d_in[5];
    const float* W2       = (const float*)d_in[6];
    const float* att_src2 = (const float*)d_in[7];
    const float* att_dst2 = (const float*)d_in[8];
    const float* b2       = (const float*)d_in[9];
    const float* Wl       = (const float*)d_in[10];
    const float* bl       = (const float*)d_in[11];
    float* out = (float*)d_out;

    int N = in_sizes[0] / 3;
    int E = in_sizes[1] / 2;
    const int* src = eidx;
    const int* dst = eidx + E;
    int NBr = (N + BN - 1) / BN;   // 764

    size_t szNHh = (size_t)N * HID * 2;          // 6.4 MB
    size_t szN4  = (size_t)N * 4;
    size_t szPK  = (size_t)NBr * BSTRIDE * 4;    // 14.1 MB

    char* ws = (char*)d_ws;
    __half* h1h    = (__half*)ws; ws += szNHh;
    __half* h2h    = (__half*)ws; ws += szNHh;
    unsigned int* packed = (unsigned int*)ws; ws += szPK;
    float*  a_s1   = (float*)ws;  ws += szN4;
    float*  a_d1   = (float*)ws;  ws += szN4;
    float*  a_s2   = (float*)ws;  ws += szN4;
    float*  a_d2   = (float*)ws;  ws += szN4;
    int*    cursor = (int*)ws;    ws += NBPAD * 4;
    int*    bar    = (int*)ws;    ws += 64;

    // fused path requires all NBr blocks co-resident (sw grid barrier).
    // Deterministic per device -> same path on every call (graph-safe).
    int dev = 0, cus = 0, maxb = 0;
    hipGetDevice(&dev);
    hipDeviceGetAttribute(&cus, hipDeviceAttributeMultiprocessorCount, dev);
    hipOccupancyMaxActiveBlocksPerMultiprocessor(&maxb, k_fused, 512, 0);
    bool fused_ok = ((long)maxb * (long)cus >= (long)NBr) && (NBr <= NBPAD);

    if (fused_ok) {
        k_zero_bar<<<1, 64, 0, stream>>>(bar);
        k_fused<<<NBr, 512, 0, stream>>>(x, src, dst,
                                         W1, att_src1, att_dst1, b1,
                                         W2, att_src2, att_dst2, b2,
                                         Wl, bl, h1h, h2h, packed,
                                         a_s1, a_d1, a_s2, a_d2,
                                         cursor, bar, out, N, E, NBr);
    } else {
        const int B = 256;
        int gridNode32 = (N * HID + B - 1) / B;
        int gridBin    = (E + CHUNK - 1) / CHUNK;
        k_transform1<<<gridNode32, B, 0, stream>>>(x, W1, att_src1, att_dst1,
                                                   h1h, a_s1, a_d1, cursor, N);
        k_binscatter<<<gridBin, B, 0, stream>>>(src, dst, cursor, packed, NBr, E);
        k_agg_mid_f<<<NBr, 512, 0, stream>>>(h1h, a_s1, a_d1, cursor, packed,
                                             b1, W2, att_src2, att_dst2,
                                             h2h, a_s2, a_d2, N);
        k_agg_out_f<<<NBr, 512, 0, stream>>>(h2h, a_s2, a_d2, cursor, packed,
                                             b2, Wl, bl, out, N);
    }
}

// Round 18
// 249.724 us; speedup vs baseline: 1.0083x; 1.0083x over previous
//
#include <hip/hip_runtime.h>
#include <hip/hip_fp16.h>

#define HID 32
#define BN 131         // nodes per bucket -> NB = ceil(100000/131) = 764
#define NBPAD 768      // padded bucket arrays (3 per thread in binscatter scan)
#define BSTRIDE 4608   // per-bucket edge capacity: mean 4194 +6.4 sigma
#define CHUNK 4096     // edges per binscatter chunk

__device__ __forceinline__ float lrelu(float x) { return x > 0.0f ? x : 0.2f * x; }

// ---------------- shared building blocks ----------------

struct BinSM {
    int stage[CHUNK];                 // 16 KB
    unsigned short sbid[CHUNK];       // 8 KB
    int lhist[NBPAD], lexcl[NBPAD], lbase[NBPAD], lcur[NBPAD];  // 12 KB
    int arr[256];                     // 1 KB
};
struct AggSM {
    int2  lpair[BSTRIDE];             // 36 KB: .x = src|dl<<17, .y = exp bits
    int   lhist[256], lscan[256], lcur[256];  // 3 KB
    float adT[BN];                    // 0.5 KB
};
union FusedSM { BinSM bin; AggSM agg; };      // ~37 KB -> 4 blocks/CU @512thr

// binscatter for one chunk, templated block size. LDS-staged sort by bucket
// so global writes are coalesced runs (R7/R12-proven). Scan runs on t<256.
template<int BLK>
__device__ __forceinline__ void binscatter_chunk(BinSM& S, int base,
        const int* __restrict__ src, const int* __restrict__ dst,
        int* __restrict__ cursor, unsigned int* __restrict__ packed,
        int NBr, int E)
{
    int t = threadIdx.x;
    for (int i = t; i < NBPAD; i += BLK) { S.lhist[i] = 0; S.lcur[i] = 0; }
    __syncthreads();
    int cnt = E - base; if (cnt > CHUNK) cnt = CHUNK;
    for (int i = t; i < cnt; i += BLK)
        atomicAdd(&S.lhist[dst[base + i] / BN], 1);
    __syncthreads();
    int b0 = 3 * t;
    int c0 = 0, c1 = 0, c2 = 0, s = 0;
    if (t < 256) {
        c0 = S.lhist[b0]; c1 = S.lhist[b0 + 1]; c2 = S.lhist[b0 + 2];
        s = c0 + c1 + c2;
        S.arr[t] = s;
    }
    __syncthreads();
    for (int o = 1; o < 256; o <<= 1) {
        int v = (t < 256 && t >= o) ? S.arr[t - o] : 0;
        __syncthreads();
        if (t < 256) S.arr[t] += v;
        __syncthreads();
    }
    if (t < 256) {
        int ex = S.arr[t] - s;
        int e0 = ex, e1 = ex + c0, e2 = ex + c0 + c1;
        S.lexcl[b0] = e0; S.lexcl[b0 + 1] = e1; S.lexcl[b0 + 2] = e2;
        for (int i = 0; i < c0; ++i) S.sbid[e0 + i] = (unsigned short)b0;
        for (int i = 0; i < c1; ++i) S.sbid[e1 + i] = (unsigned short)(b0 + 1);
        for (int i = 0; i < c2; ++i) S.sbid[e2 + i] = (unsigned short)(b0 + 2);
    }
    for (int b = t; b < NBr; b += BLK)
        if (S.lhist[b]) S.lbase[b] = b * BSTRIDE + atomicAdd(&cursor[b], S.lhist[b]);
    __syncthreads();
    for (int i = t; i < cnt; i += BLK) {
        int d = dst[base + i];
        int sv = src[base + i];
        int b = d / BN;
        int dl = d - b * BN;
        int idx = S.lexcl[b] + atomicAdd(&S.lcur[b], 1);
        S.stage[idx] = (int)((unsigned)sv | ((unsigned)dl << 17));
    }
    __syncthreads();
    for (int i = t; i < cnt; i += BLK) {
        int b = S.sbid[i];
        int gpos = S.lbase[b] + (i - S.lexcl[b]);
        if (gpos < (b + 1) * BSTRIDE)
            packed[gpos] = (unsigned)S.stage[i];
    }
}

// in-block CSR+exp build: node-sorted int2 pairs {packed word, exp bits}.
template<int BLK>
__device__ __forceinline__ void build_csr_pair(int2* lpair, float* adT,
        int* lhist, int* lscan, int* lcur,
        const unsigned int* __restrict__ pk, int cnt,
        const float* __restrict__ a_s, const float* __restrict__ a_d,
        int nodeBase, int N)
{
    int t = threadIdx.x;
    if (t < 256) { lhist[t] = 0; lcur[t] = 0; }
    if (t < BN) { int n = nodeBase + t; adT[t] = (n < N) ? a_d[n] : 0.0f; }
    __syncthreads();
    for (int i = t; i < cnt; i += BLK)
        atomicAdd(&lhist[(pk[i] >> 17) & 255], 1);
    __syncthreads();
    if (t < 256) lscan[t] = lhist[t];
    __syncthreads();
    for (int o = 1; o < 256; o <<= 1) {
        int v = (t < 256 && t >= o) ? lscan[t - o] : 0;
        __syncthreads();
        if (t < 256) lscan[t] += v;
        __syncthreads();
    }
    for (int i = t; i < cnt; i += BLK) {
        unsigned p = pk[i];
        int dl = (p >> 17) & 255;
        int sv = (int)(p & 0x1FFFF);
        float e = __expf(lrelu(a_s[sv] + adT[dl]));
        int pos = atomicAdd(&lcur[dl], 1);
        lpair[(lscan[dl] - lhist[dl]) + pos] = make_int2((int)p, __float_as_int(e));
    }
    __syncthreads();
}

// agg inner loop: 16 lanes/node, den in-loop, unroll x8; single b64 LDS read
// per edge (int2 pair), src recovered with one AND.
__device__ __forceinline__ void agg_node(const __half* __restrict__ hh,
                                         float ex_self, const float* __restrict__ b,
                                         int n, int f,
                                         const int2* lpair,
                                         int off, int dg, float& vx, float& vy)
{
    float den = ex_self;
    float2 hs = __half22float2(*(const __half2*)(hh + (size_t)n * HID + 2 * f));
    float accx = ex_self * hs.x;
    float accy = ex_self * hs.y;
    int j = 0;
    for (; j + 8 <= dg; j += 8) {
        int2 p0 = lpair[off + j + 0], p1 = lpair[off + j + 1];
        int2 p2 = lpair[off + j + 2], p3 = lpair[off + j + 3];
        int2 p4 = lpair[off + j + 4], p5 = lpair[off + j + 5];
        int2 p6 = lpair[off + j + 6], p7 = lpair[off + j + 7];
        int s0 = p0.x & 0x1FFFF, s1 = p1.x & 0x1FFFF;
        int s2 = p2.x & 0x1FFFF, s3 = p3.x & 0x1FFFF;
        int s4 = p4.x & 0x1FFFF, s5 = p5.x & 0x1FFFF;
        int s6 = p6.x & 0x1FFFF, s7 = p7.x & 0x1FFFF;
        __half2 h0 = *(const __half2*)(hh + (size_t)s0 * HID + 2 * f);
        __half2 h1 = *(const __half2*)(hh + (size_t)s1 * HID + 2 * f);
        __half2 h2 = *(const __half2*)(hh + (size_t)s2 * HID + 2 * f);
        __half2 h3 = *(const __half2*)(hh + (size_t)s3 * HID + 2 * f);
        __half2 h4 = *(const __half2*)(hh + (size_t)s4 * HID + 2 * f);
        __half2 h5 = *(const __half2*)(hh + (size_t)s5 * HID + 2 * f);
        __half2 h6 = *(const __half2*)(hh + (size_t)s6 * HID + 2 * f);
        __half2 h7 = *(const __half2*)(hh + (size_t)s7 * HID + 2 * f);
        float e0 = __int_as_float(p0.y), e1 = __int_as_float(p1.y);
        float e2 = __int_as_float(p2.y), e3 = __int_as_float(p3.y);
        float e4 = __int_as_float(p4.y), e5 = __int_as_float(p5.y);
        float e6 = __int_as_float(p6.y), e7 = __int_as_float(p7.y);
        float2 q0 = __half22float2(h0), q1 = __half22float2(h1);
        float2 q2 = __half22float2(h2), q3 = __half22float2(h3);
        float2 q4 = __half22float2(h4), q5 = __half22float2(h5);
        float2 q6 = __half22float2(h6), q7 = __half22float2(h7);
        den += ((e0 + e1) + (e2 + e3)) + ((e4 + e5) + (e6 + e7));
        accx = fmaf(e0, q0.x, accx); accy = fmaf(e0, q0.y, accy);
        accx = fmaf(e1, q1.x, accx); accy = fmaf(e1, q1.y, accy);
        accx = fmaf(e2, q2.x, accx); accy = fmaf(e2, q2.y, accy);
        accx = fmaf(e3, q3.x, accx); accy = fmaf(e3, q3.y, accy);
        accx = fmaf(e4, q4.x, accx); accy = fmaf(e4, q4.y, accy);
        accx = fmaf(e5, q5.x, accx); accy = fmaf(e5, q5.y, accy);
        accx = fmaf(e6, q6.x, accx); accy = fmaf(e6, q6.y, accy);
        accx = fmaf(e7, q7.x, accx); accy = fmaf(e7, q7.y, accy);
    }
    for (; j < dg; ++j) {
        int2 p0 = lpair[off + j];
        int s0 = p0.x & 0x1FFFF;
        float e0 = __int_as_float(p0.y);
        float2 q0 = __half22float2(*(const __half2*)(hh + (size_t)s0 * HID + 2 * f));
        den += e0;
        accx = fmaf(e0, q0.x, accx);
        accy = fmaf(e0, q0.y, accy);
    }
    float inv = 1.0f / (den + 1e-16f);
    vx = fmaxf(accx * inv + b[2 * f], 0.0f);
    vy = fmaxf(accy * inv + b[2 * f + 1], 0.0f);
}

// layer-1 epilogue: W2 transform + layer-2 attention halves (width-16)
__device__ __forceinline__ void epi_mid(int n, int f, float vx, float vy,
        const float* __restrict__ W2, const float* __restrict__ as2w,
        const float* __restrict__ ad2w,
        __half* __restrict__ hh_out, float* __restrict__ as_out,
        float* __restrict__ ad_out)
{
    float hx = 0.0f, hy = 0.0f;
    #pragma unroll
    for (int k = 0; k < 16; ++k) {
        float va = __shfl(vx, k, 16);
        float vb = __shfl(vy, k, 16);
        float2 w0 = *(const float2*)(W2 + (2 * k) * HID + 2 * f);
        float2 w1 = *(const float2*)(W2 + (2 * k + 1) * HID + 2 * f);
        hx = fmaf(va, w0.x, hx); hy = fmaf(va, w0.y, hy);
        hx = fmaf(vb, w1.x, hx); hy = fmaf(vb, w1.y, hy);
    }
    *(__half2*)(hh_out + (size_t)n * HID + 2 * f) = __floats2half2_rn(hx, hy);
    float as = hx * as2w[2 * f] + hy * as2w[2 * f + 1];
    float ad = hx * ad2w[2 * f] + hy * ad2w[2 * f + 1];
    #pragma unroll
    for (int m2 = 8; m2 >= 1; m2 >>= 1) {
        as += __shfl_xor(as, m2, 16);
        ad += __shfl_xor(ad, m2, 16);
    }
    if (f == 0) { as_out[n] = as; ad_out[n] = ad; }
}

// software grid barrier: monotonic counter, device-scope; requires all blocks
// resident (checked on host via occupancy query before choosing this path).
__device__ __forceinline__ void grid_bar(int* bar, int target)
{
    __syncthreads();
    if (threadIdx.x == 0) {
        __threadfence();
        __hip_atomic_fetch_add(bar, 1, __ATOMIC_RELEASE, __HIP_MEMORY_SCOPE_AGENT);
        while (__hip_atomic_load(bar, __ATOMIC_ACQUIRE, __HIP_MEMORY_SCOPE_AGENT) < target)
            __builtin_amdgcn_s_sleep(8);
        __threadfence();
    }
    __syncthreads();
}

__global__ void k_zero_bar(int* __restrict__ bar)
{
    if (threadIdx.x < 4) bar[threadIdx.x] = 0;
}

// ---------------- fused persistent kernel (512 threads) ----------------
__global__ void __launch_bounds__(512) k_fused(
    const float* __restrict__ x, const int* __restrict__ src, const int* __restrict__ dst,
    const float* __restrict__ W1, const float* __restrict__ as1w,
    const float* __restrict__ ad1w, const float* __restrict__ b1,
    const float* __restrict__ W2, const float* __restrict__ as2w,
    const float* __restrict__ ad2w, const float* __restrict__ b2,
    const float* __restrict__ Wl, const float* __restrict__ bl,
    __half* __restrict__ h1h, __half* __restrict__ h2h,
    unsigned int* __restrict__ packed,
    float* __restrict__ a_s1, float* __restrict__ a_d1,
    float* __restrict__ a_s2, float* __restrict__ a_d2,
    int* __restrict__ cursor, int* __restrict__ bar,
    float* __restrict__ out, int N, int E, int NBr)
{
    __shared__ FusedSM sm;
    int t = threadIdx.x, bk = blockIdx.x;
    int nth = gridDim.x * 512, gtid = bk * 512 + t;

    // ---- phase 0: transform + cursor zero ----
    for (int i = gtid; i < NBPAD; i += nth) cursor[i] = 0;
    for (int idx = gtid; idx < N * HID; idx += nth) {
        int n = idx >> 5, f = idx & 31;
        float x0 = x[n * 3 + 0], x1 = x[n * 3 + 1], x2 = x[n * 3 + 2];
        float hv = x0 * W1[f] + x1 * W1[HID + f] + x2 * W1[2 * HID + f];
        h1h[(size_t)n * HID + f] = __float2half(hv);
        float as = hv * as1w[f];
        float ad = hv * ad1w[f];
        #pragma unroll
        for (int m = 16; m >= 1; m >>= 1) {
            as += __shfl_xor(as, m, 32);
            ad += __shfl_xor(ad, m, 32);
        }
        if (f == 0) { a_s1[n] = as; a_d1[n] = ad; }
    }
    grid_bar(bar, gridDim.x);

    // ---- phase 1: binscatter (grid-stride over chunks) ----
    int nch = (E + CHUNK - 1) / CHUNK;
    for (int c = bk; c < nch; c += gridDim.x) {
        binscatter_chunk<512>(sm.bin, c * CHUNK, src, dst, cursor, packed, NBr, E);
        __syncthreads();
    }
    grid_bar(bar, 2 * gridDim.x);

    // ---- phase 2: build + agg layer 1 ----
    int cnt = cursor[bk]; if (cnt > BSTRIDE) cnt = BSTRIDE;
    build_csr_pair<512>(sm.agg.lpair, sm.agg.adT,
                        sm.agg.lhist, sm.agg.lscan, sm.agg.lcur,
                        packed + (size_t)bk * BSTRIDE, cnt, a_s1, a_d1, bk * BN, N);
    {
        int g = t >> 4, f = t & 15;      // 32 groups of 16 lanes
        for (int dl = g; dl < BN; dl += 32) {
            int n = bk * BN + dl;
            if (n >= N) continue;
            int off = sm.agg.lscan[dl] - sm.agg.lhist[dl];
            int dg = sm.agg.lhist[dl];
            float exs = __expf(lrelu(a_s1[n] + sm.agg.adT[dl]));
            float vx, vy;
            agg_node(h1h, exs, b1, n, f, sm.agg.lpair, off, dg, vx, vy);
            epi_mid(n, f, vx, vy, W2, as2w, ad2w, h2h, a_s2, a_d2);
        }
    }
    grid_bar(bar, 3 * gridDim.x);

    // ---- phase 3: re-exp in place (dl comes from the kept packed word —
    //      no binary search) + agg layer 2 + head ----
    if (t < BN) { int n = bk * BN + t; sm.agg.adT[t] = (n < N) ? a_d2[n] : 0.0f; }
    __syncthreads();
    for (int i = t; i < cnt; i += 512) {
        int pw = sm.agg.lpair[i].x;
        int sv = pw & 0x1FFFF;
        int dl = (pw >> 17) & 255;
        float e = __expf(lrelu(a_s2[sv] + sm.agg.adT[dl]));
        sm.agg.lpair[i] = make_int2(pw, __float_as_int(e));
    }
    __syncthreads();
    {
        int g = t >> 4, f = t & 15;
        for (int dl = g; dl < BN; dl += 32) {
            int n = bk * BN + dl;
            if (n >= N) continue;
            int off = sm.agg.lscan[dl] - sm.agg.lhist[dl];
            int dg = sm.agg.lhist[dl];
            float exs = __expf(lrelu(a_s2[n] + sm.agg.adT[dl]));
            float vx, vy;
            agg_node(h2h, exs, b2, n, f, sm.agg.lpair, off, dg, vx, vy);
            float y = vx * Wl[2 * f] + vy * Wl[2 * f + 1];
            #pragma unroll
            for (int m2 = 8; m2 >= 1; m2 >>= 1)
                y += __shfl_xor(y, m2, 16);
            if (f == 0) out[n] = y + bl[0];
        }
    }
}

// ---------------- fallback path (4-kernel, same building blocks) ----------------

__global__ void k_transform1(const float* __restrict__ x,
                             const float* __restrict__ W1,
                             const float* __restrict__ att_src,
                             const float* __restrict__ att_dst,
                             __half* __restrict__ hh,
                             float* __restrict__ a_s,
                             float* __restrict__ a_d,
                             int* __restrict__ cursor, int N)
{
    int tid = blockIdx.x * blockDim.x + threadIdx.x;
    if (tid < NBPAD) cursor[tid] = 0;
    int n = tid >> 5, f = tid & 31;
    if (n >= N) return;
    float x0 = x[n * 3 + 0], x1 = x[n * 3 + 1], x2 = x[n * 3 + 2];
    float hv = x0 * W1[f] + x1 * W1[HID + f] + x2 * W1[2 * HID + f];
    hh[(size_t)n * HID + f] = __float2half(hv);
    float as = hv * att_src[f];
    float ad = hv * att_dst[f];
    #pragma unroll
    for (int m = 16; m >= 1; m >>= 1) {
        as += __shfl_xor(as, m, 32);
        ad += __shfl_xor(ad, m, 32);
    }
    if (f == 0) { a_s[n] = as; a_d[n] = ad; }
}

__global__ void __launch_bounds__(256) k_binscatter(const int* __restrict__ src,
        const int* __restrict__ dst, int* __restrict__ cursor,
        unsigned int* __restrict__ packed, int NBr, int E)
{
    __shared__ BinSM S;
    binscatter_chunk<256>(S, blockIdx.x * CHUNK, src, dst, cursor, packed, NBr, E);
}

__global__ void __launch_bounds__(512) k_agg_mid_f(const __half* __restrict__ hh,
        const float* __restrict__ a_s, const float* __restrict__ a_d,
        const int* __restrict__ cursor, const unsigned int* __restrict__ packed,
        const float* __restrict__ b1, const float* __restrict__ W2,
        const float* __restrict__ as2w, const float* __restrict__ ad2w,
        __half* __restrict__ hh_out, float* __restrict__ as_out,
        float* __restrict__ ad_out, int N)
{
    __shared__ AggSM S;
    int bk = blockIdx.x, t = threadIdx.x;
    int cnt = cursor[bk]; if (cnt > BSTRIDE) cnt = BSTRIDE;
    build_csr_pair<512>(S.lpair, S.adT, S.lhist, S.lscan, S.lcur,
                        packed + (size_t)bk * BSTRIDE, cnt, a_s, a_d, bk * BN, N);
    int g = t >> 4, f = t & 15;
    for (int dl = g; dl < BN; dl += 32) {
        int n = bk * BN + dl;
        if (n >= N) continue;
        int off = S.lscan[dl] - S.lhist[dl];
        int dg = S.lhist[dl];
        float exs = __expf(lrelu(a_s[n] + S.adT[dl]));
        float vx, vy;
        agg_node(hh, exs, b1, n, f, S.lpair, off, dg, vx, vy);
        epi_mid(n, f, vx, vy, W2, as2w, ad2w, hh_out, as_out, ad_out);
    }
}

__global__ void __launch_bounds__(512) k_agg_out_f(const __half* __restrict__ hh,
        const float* __restrict__ a_s, const float* __restrict__ a_d,
        const int* __restrict__ cursor, const unsigned int* __restrict__ packed,
        const float* __restrict__ b2, const float* __restrict__ Wl,
        const float* __restrict__ bl, float* __restrict__ out, int N)
{
    __shared__ AggSM S;
    int bk = blockIdx.x, t = threadIdx.x;
    int cnt = cursor[bk]; if (cnt > BSTRIDE) cnt = BSTRIDE;
    build_csr_pair<512>(S.lpair, S.adT, S.lhist, S.lscan, S.lcur,
                        packed + (size_t)bk * BSTRIDE, cnt, a_s, a_d, bk * BN, N);
    int g = t >> 4, f = t & 15;
    for (int dl = g; dl < BN; dl += 32) {
        int n = bk * BN + dl;
        if (n >= N) continue;
        int off = S.lscan[dl] - S.lhist[dl];
        int dg = S.lhist[dl];
        float exs = __expf(lrelu(a_s[n] + S.adT[dl]));
        float vx, vy;
        agg_node(hh, exs, b2, n, f, S.lpair, off, dg, vx, vy);
        float y = vx * Wl[2 * f] + vy * Wl[2 * f + 1];
        #pragma unroll
        for (int m2 = 8; m2 >= 1; m2 >>= 1)
            y += __shfl_xor(y, m2, 16);
        if (f == 0) out[n] = y + bl[0];
    }
}

extern "C" void kernel_launch(void* const* d_in, const int* in_sizes, int n_in,
                              void* d_out, int out_size, void* d_ws, size_t ws_size,
                              hipStream_t stream)
{
    const float* x        = (const float*)d_in[0];
    const int*   eidx     = (const int*)d_in[1];
    const float* W1       = (const float*)d_in[2];
    const float* att_src1 = (const float*)d_in[3];
    const float* att_dst1 = (const float*)d_in[4];
    const float* b1       = (const float*)d_in[5];
    const float* W2       = (const float*)d_in[6];
    const float* att_src2 = (const float*)d_in[7];
    const float* att_dst2 = (const float*)d_in[8];
    const float* b2       = (const float*)d_in[9];
    const float* Wl       = (const float*)d_in[10];
    const float* bl       = (const float*)d_in[11];
    float* out = (float*)d_out;

    int N = in_sizes[0] / 3;
    int E = in_sizes[1] / 2;
    const int* src = eidx;
    const int* dst = eidx + E;
    int NBr = (N + BN - 1) / BN;   // 764

    size_t szNHh = (size_t)N * HID * 2;          // 6.4 MB
    size_t szN4  = (size_t)N * 4;
    size_t szPK  = (size_t)NBr * BSTRIDE * 4;    // 14.1 MB

    char* ws = (char*)d_ws;
    __half* h1h    = (__half*)ws; ws += szNHh;
    __half* h2h    = (__half*)ws; ws += szNHh;
    unsigned int* packed = (unsigned int*)ws; ws += szPK;
    float*  a_s1   = (float*)ws;  ws += szN4;
    float*  a_d1   = (float*)ws;  ws += szN4;
    float*  a_s2   = (float*)ws;  ws += szN4;
    float*  a_d2   = (float*)ws;  ws += szN4;
    int*    cursor = (int*)ws;    ws += NBPAD * 4;
    int*    bar    = (int*)ws;    ws += 64;

    // fused path requires all NBr blocks co-resident (sw grid barrier).
    // Deterministic per device -> same path on every call (graph-safe).
    int dev = 0, cus = 0, maxb = 0;
    hipGetDevice(&dev);
    hipDeviceGetAttribute(&cus, hipDeviceAttributeMultiprocessorCount, dev);
    hipOccupancyMaxActiveBlocksPerMultiprocessor(&maxb, k_fused, 512, 0);
    bool fused_ok = ((long)maxb * (long)cus >= (long)NBr) && (NBr <= NBPAD);

    if (fused_ok) {
        k_zero_bar<<<1, 64, 0, stream>>>(bar);
        k_fused<<<NBr, 512, 0, stream>>>(x, src, dst,
                                         W1, att_src1, att_dst1, b1,
                                         W2, att_src2, att_dst2, b2,
                                         Wl, bl, h1h, h2h, packed,
                                         a_s1, a_d1, a_s2, a_d2,
                                         cursor, bar, out, N, E, NBr);
    } else {
        const int B = 256;
        int gridNode32 = (N * HID + B - 1) / B;
        int gridBin    = (E + CHUNK - 1) / CHUNK;
        k_transform1<<<gridNode32, B, 0, stream>>>(x, W1, att_src1, att_dst1,
                                                   h1h, a_s1, a_d1, cursor, N);
        k_binscatter<<<gridBin, B, 0, stream>>>(src, dst, cursor, packed, NBr, E);
        k_agg_mid_f<<<NBr, 512, 0, stream>>>(h1h, a_s1, a_d1, cursor, packed,
                                             b1, W2, att_src2, att_dst2,
                                             h2h, a_s2, a_d2, N);
        k_agg_out_f<<<NBr, 512, 0, stream>>>(h2h, a_s2, a_d2, cursor, packed,
                                             b2, Wl, bl, out, N);
    }
}

// Round 19
// 246.484 us; speedup vs baseline: 1.0216x; 1.0131x over previous
//
#include <hip/hip_runtime.h>
#include <hip/hip_fp16.h>

#define HID 32
#define BN 131         // nodes per bucket -> NB = ceil(100000/131) = 764
#define NBPAD 768      // padded bucket arrays (3 per thread in binscatter scan)
#define BSTRIDE 4608   // per-bucket edge capacity: mean 4194 +6.4 sigma
#define CHUNK 4096     // edges per binscatter chunk

__device__ __forceinline__ float lrelu(float x) { return x > 0.0f ? x : 0.2f * x; }

// ---------------- building blocks ----------------

struct BinSM {
    int stage[CHUNK];                 // 16 KB
    unsigned short sbid[CHUNK];       // 8 KB
    int lhist[NBPAD], lexcl[NBPAD], lbase[NBPAD], lcur[NBPAD];  // 12 KB
    int arr[256];                     // 1 KB
};
struct AggSM {
    int2  lpair[BSTRIDE];             // 36 KB: .x = src|dl<<17, .y = exp bits
    int   lhist[256], lscan[256], lcur[256];  // 3 KB
    float adT[BN];                    // 0.5 KB
};

// binscatter for one chunk, templated block size. LDS-staged sort by bucket
// so global writes are coalesced runs (R7/R12-proven). Scan runs on t<256.
template<int BLK>
__device__ __forceinline__ void binscatter_chunk(BinSM& S, int base,
        const int* __restrict__ src, const int* __restrict__ dst,
        int* __restrict__ cursor, unsigned int* __restrict__ packed,
        int NBr, int E)
{
    int t = threadIdx.x;
    for (int i = t; i < NBPAD; i += BLK) { S.lhist[i] = 0; S.lcur[i] = 0; }
    __syncthreads();
    int cnt = E - base; if (cnt > CHUNK) cnt = CHUNK;
    for (int i = t; i < cnt; i += BLK)
        atomicAdd(&S.lhist[dst[base + i] / BN], 1);
    __syncthreads();
    int b0 = 3 * t;
    int c0 = 0, c1 = 0, c2 = 0, s = 0;
    if (t < 256) {
        c0 = S.lhist[b0]; c1 = S.lhist[b0 + 1]; c2 = S.lhist[b0 + 2];
        s = c0 + c1 + c2;
        S.arr[t] = s;
    }
    __syncthreads();
    for (int o = 1; o < 256; o <<= 1) {
        int v = (t < 256 && t >= o) ? S.arr[t - o] : 0;
        __syncthreads();
        if (t < 256) S.arr[t] += v;
        __syncthreads();
    }
    if (t < 256) {
        int ex = S.arr[t] - s;
        int e0 = ex, e1 = ex + c0, e2 = ex + c0 + c1;
        S.lexcl[b0] = e0; S.lexcl[b0 + 1] = e1; S.lexcl[b0 + 2] = e2;
        for (int i = 0; i < c0; ++i) S.sbid[e0 + i] = (unsigned short)b0;
        for (int i = 0; i < c1; ++i) S.sbid[e1 + i] = (unsigned short)(b0 + 1);
        for (int i = 0; i < c2; ++i) S.sbid[e2 + i] = (unsigned short)(b0 + 2);
    }
    for (int b = t; b < NBr; b += BLK)
        if (S.lhist[b]) S.lbase[b] = b * BSTRIDE + atomicAdd(&cursor[b], S.lhist[b]);
    __syncthreads();
    for (int i = t; i < cnt; i += BLK) {
        int d = dst[base + i];
        int sv = src[base + i];
        int b = d / BN;
        int dl = d - b * BN;
        int idx = S.lexcl[b] + atomicAdd(&S.lcur[b], 1);
        S.stage[idx] = (int)((unsigned)sv | ((unsigned)dl << 17));
    }
    __syncthreads();
    for (int i = t; i < cnt; i += BLK) {
        int b = S.sbid[i];
        int gpos = S.lbase[b] + (i - S.lexcl[b]);
        if (gpos < (b + 1) * BSTRIDE)
            packed[gpos] = (unsigned)S.stage[i];
    }
}

// in-block CSR+exp build: node-sorted int2 pairs {packed word, exp bits}.
template<int BLK>
__device__ __forceinline__ void build_csr_pair(int2* lpair, float* adT,
        int* lhist, int* lscan, int* lcur,
        const unsigned int* __restrict__ pk, int cnt,
        const float* __restrict__ a_s, const float* __restrict__ a_d,
        int nodeBase, int N)
{
    int t = threadIdx.x;
    if (t < 256) { lhist[t] = 0; lcur[t] = 0; }
    if (t < BN) { int n = nodeBase + t; adT[t] = (n < N) ? a_d[n] : 0.0f; }
    __syncthreads();
    for (int i = t; i < cnt; i += BLK)
        atomicAdd(&lhist[(pk[i] >> 17) & 255], 1);
    __syncthreads();
    if (t < 256) lscan[t] = lhist[t];
    __syncthreads();
    for (int o = 1; o < 256; o <<= 1) {
        int v = (t < 256 && t >= o) ? lscan[t - o] : 0;
        __syncthreads();
        if (t < 256) lscan[t] += v;
        __syncthreads();
    }
    for (int i = t; i < cnt; i += BLK) {
        unsigned p = pk[i];
        int dl = (p >> 17) & 255;
        int sv = (int)(p & 0x1FFFF);
        float e = __expf(lrelu(a_s[sv] + adT[dl]));
        int pos = atomicAdd(&lcur[dl], 1);
        lpair[(lscan[dl] - lhist[dl]) + pos] = make_int2((int)p, __float_as_int(e));
    }
    __syncthreads();
}

// agg inner loop: 16 lanes/node, den in-loop, unroll x8; single b64 LDS read
// per edge (int2 pair), src recovered with one AND.
__device__ __forceinline__ void agg_node(const __half* __restrict__ hh,
                                         float ex_self, const float* __restrict__ b,
                                         int n, int f,
                                         const int2* lpair,
                                         int off, int dg, float& vx, float& vy)
{
    float den = ex_self;
    float2 hs = __half22float2(*(const __half2*)(hh + (size_t)n * HID + 2 * f));
    float accx = ex_self * hs.x;
    float accy = ex_self * hs.y;
    int j = 0;
    for (; j + 8 <= dg; j += 8) {
        int2 p0 = lpair[off + j + 0], p1 = lpair[off + j + 1];
        int2 p2 = lpair[off + j + 2], p3 = lpair[off + j + 3];
        int2 p4 = lpair[off + j + 4], p5 = lpair[off + j + 5];
        int2 p6 = lpair[off + j + 6], p7 = lpair[off + j + 7];
        int s0 = p0.x & 0x1FFFF, s1 = p1.x & 0x1FFFF;
        int s2 = p2.x & 0x1FFFF, s3 = p3.x & 0x1FFFF;
        int s4 = p4.x & 0x1FFFF, s5 = p5.x & 0x1FFFF;
        int s6 = p6.x & 0x1FFFF, s7 = p7.x & 0x1FFFF;
        __half2 h0 = *(const __half2*)(hh + (size_t)s0 * HID + 2 * f);
        __half2 h1 = *(const __half2*)(hh + (size_t)s1 * HID + 2 * f);
        __half2 h2 = *(const __half2*)(hh + (size_t)s2 * HID + 2 * f);
        __half2 h3 = *(const __half2*)(hh + (size_t)s3 * HID + 2 * f);
        __half2 h4 = *(const __half2*)(hh + (size_t)s4 * HID + 2 * f);
        __half2 h5 = *(const __half2*)(hh + (size_t)s5 * HID + 2 * f);
        __half2 h6 = *(const __half2*)(hh + (size_t)s6 * HID + 2 * f);
        __half2 h7 = *(const __half2*)(hh + (size_t)s7 * HID + 2 * f);
        float e0 = __int_as_float(p0.y), e1 = __int_as_float(p1.y);
        float e2 = __int_as_float(p2.y), e3 = __int_as_float(p3.y);
        float e4 = __int_as_float(p4.y), e5 = __int_as_float(p5.y);
        float e6 = __int_as_float(p6.y), e7 = __int_as_float(p7.y);
        float2 q0 = __half22float2(h0), q1 = __half22float2(h1);
        float2 q2 = __half22float2(h2), q3 = __half22float2(h3);
        float2 q4 = __half22float2(h4), q5 = __half22float2(h5);
        float2 q6 = __half22float2(h6), q7 = __half22float2(h7);
        den += ((e0 + e1) + (e2 + e3)) + ((e4 + e5) + (e6 + e7));
        accx = fmaf(e0, q0.x, accx); accy = fmaf(e0, q0.y, accy);
        accx = fmaf(e1, q1.x, accx); accy = fmaf(e1, q1.y, accy);
        accx = fmaf(e2, q2.x, accx); accy = fmaf(e2, q2.y, accy);
        accx = fmaf(e3, q3.x, accx); accy = fmaf(e3, q3.y, accy);
        accx = fmaf(e4, q4.x, accx); accy = fmaf(e4, q4.y, accy);
        accx = fmaf(e5, q5.x, accx); accy = fmaf(e5, q5.y, accy);
        accx = fmaf(e6, q6.x, accx); accy = fmaf(e6, q6.y, accy);
        accx = fmaf(e7, q7.x, accx); accy = fmaf(e7, q7.y, accy);
    }
    for (; j < dg; ++j) {
        int2 p0 = lpair[off + j];
        int s0 = p0.x & 0x1FFFF;
        float e0 = __int_as_float(p0.y);
        float2 q0 = __half22float2(*(const __half2*)(hh + (size_t)s0 * HID + 2 * f));
        den += e0;
        accx = fmaf(e0, q0.x, accx);
        accy = fmaf(e0, q0.y, accy);
    }
    float inv = 1.0f / (den + 1e-16f);
    vx = fmaxf(accx * inv + b[2 * f], 0.0f);
    vy = fmaxf(accy * inv + b[2 * f + 1], 0.0f);
}

// layer-1 epilogue: W2 transform + layer-2 attention halves (width-16)
__device__ __forceinline__ void epi_mid(int n, int f, float vx, float vy,
        const float* __restrict__ W2, const float* __restrict__ as2w,
        const float* __restrict__ ad2w,
        __half* __restrict__ hh_out, float* __restrict__ as_out,
        float* __restrict__ ad_out)
{
    float hx = 0.0f, hy = 0.0f;
    #pragma unroll
    for (int k = 0; k < 16; ++k) {
        float va = __shfl(vx, k, 16);
        float vb = __shfl(vy, k, 16);
        float2 w0 = *(const float2*)(W2 + (2 * k) * HID + 2 * f);
        float2 w1 = *(const float2*)(W2 + (2 * k + 1) * HID + 2 * f);
        hx = fmaf(va, w0.x, hx); hy = fmaf(va, w0.y, hy);
        hx = fmaf(vb, w1.x, hx); hy = fmaf(vb, w1.y, hy);
    }
    *(__half2*)(hh_out + (size_t)n * HID + 2 * f) = __floats2half2_rn(hx, hy);
    float as = hx * as2w[2 * f] + hy * as2w[2 * f + 1];
    float ad = hx * ad2w[2 * f] + hy * ad2w[2 * f + 1];
    #pragma unroll
    for (int m2 = 8; m2 >= 1; m2 >>= 1) {
        as += __shfl_xor(as, m2, 16);
        ad += __shfl_xor(ad, m2, 16);
    }
    if (f == 0) { as_out[n] = as; ad_out[n] = ad; }
}

// ---------------- kernels ----------------

__global__ void k_transform1(const float* __restrict__ x,
                             const float* __restrict__ W1,
                             const float* __restrict__ att_src,
                             const float* __restrict__ att_dst,
                             __half* __restrict__ hh,
                             float* __restrict__ a_s,
                             float* __restrict__ a_d,
                             int* __restrict__ cursor, int N)
{
    int tid = blockIdx.x * blockDim.x + threadIdx.x;
    if (tid < NBPAD) cursor[tid] = 0;
    int n = tid >> 5, f = tid & 31;
    if (n >= N) return;
    float x0 = x[n * 3 + 0], x1 = x[n * 3 + 1], x2 = x[n * 3 + 2];
    float hv = x0 * W1[f] + x1 * W1[HID + f] + x2 * W1[2 * HID + f];
    hh[(size_t)n * HID + f] = __float2half(hv);
    float as = hv * att_src[f];
    float ad = hv * att_dst[f];
    #pragma unroll
    for (int m = 16; m >= 1; m >>= 1) {
        as += __shfl_xor(as, m, 32);
        ad += __shfl_xor(ad, m, 32);
    }
    if (f == 0) { a_s[n] = as; a_d[n] = ad; }
}

// 512 threads per chunk: halves per-thread edge work vs the 256-thread form.
// LDS 37 KB -> 4 blocks/CU allowed; grid 782 ~ 3.05/CU.
__global__ void __launch_bounds__(512) k_binscatter(const int* __restrict__ src,
        const int* __restrict__ dst, int* __restrict__ cursor,
        unsigned int* __restrict__ packed, int NBr, int E)
{
    __shared__ BinSM S;
    binscatter_chunk<512>(S, blockIdx.x * CHUNK, src, dst, cursor, packed, NBr, E);
}

__global__ void __launch_bounds__(512) k_agg_mid_f(const __half* __restrict__ hh,
        const float* __restrict__ a_s, const float* __restrict__ a_d,
        const int* __restrict__ cursor, const unsigned int* __restrict__ packed,
        const float* __restrict__ b1, const float* __restrict__ W2,
        const float* __restrict__ as2w, const float* __restrict__ ad2w,
        __half* __restrict__ hh_out, float* __restrict__ as_out,
        float* __restrict__ ad_out, int N)
{
    __shared__ AggSM S;
    int bk = blockIdx.x, t = threadIdx.x;
    int cnt = cursor[bk]; if (cnt > BSTRIDE) cnt = BSTRIDE;
    build_csr_pair<512>(S.lpair, S.adT, S.lhist, S.lscan, S.lcur,
                        packed + (size_t)bk * BSTRIDE, cnt, a_s, a_d, bk * BN, N);
    int g = t >> 4, f = t & 15;
    for (int dl = g; dl < BN; dl += 32) {
        int n = bk * BN + dl;
        if (n >= N) continue;
        int off = S.lscan[dl] - S.lhist[dl];
        int dg = S.lhist[dl];
        float exs = __expf(lrelu(a_s[n] + S.adT[dl]));
        float vx, vy;
        agg_node(hh, exs, b1, n, f, S.lpair, off, dg, vx, vy);
        epi_mid(n, f, vx, vy, W2, as2w, ad2w, hh_out, as_out, ad_out);
    }
}

__global__ void __launch_bounds__(512) k_agg_out_f(const __half* __restrict__ hh,
        const float* __restrict__ a_s, const float* __restrict__ a_d,
        const int* __restrict__ cursor, const unsigned int* __restrict__ packed,
        const float* __restrict__ b2, const float* __restrict__ Wl,
        const float* __restrict__ bl, float* __restrict__ out, int N)
{
    __shared__ AggSM S;
    int bk = blockIdx.x, t = threadIdx.x;
    int cnt = cursor[bk]; if (cnt > BSTRIDE) cnt = BSTRIDE;
    build_csr_pair<512>(S.lpair, S.adT, S.lhist, S.lscan, S.lcur,
                        packed + (size_t)bk * BSTRIDE, cnt, a_s, a_d, bk * BN, N);
    int g = t >> 4, f = t & 15;
    for (int dl = g; dl < BN; dl += 32) {
        int n = bk * BN + dl;
        if (n >= N) continue;
        int off = S.lscan[dl] - S.lhist[dl];
        int dg = S.lhist[dl];
        float exs = __expf(lrelu(a_s[n] + S.adT[dl]));
        float vx, vy;
        agg_node(hh, exs, b2, n, f, S.lpair, off, dg, vx, vy);
        float y = vx * Wl[2 * f] + vy * Wl[2 * f + 1];
        #pragma unroll
        for (int m2 = 8; m2 >= 1; m2 >>= 1)
            y += __shfl_xor(y, m2, 16);
        if (f == 0) out[n] = y + bl[0];
    }
}

extern "C" void kernel_launch(void* const* d_in, const int* in_sizes, int n_in,
                              void* d_out, int out_size, void* d_ws, size_t ws_size,
                              hipStream_t stream)
{
    const float* x        = (const float*)d_in[0];
    const int*   eidx     = (const int*)d_in[1];
    const float* W1       = (const float*)d_in[2];
    const float* att_src1 = (const float*)d_in[3];
    const float* att_dst1 = (const float*)d_in[4];
    const float* b1       = (const float*)d_in[5];
    const float* W2       = (const float*)d_in[6];
    const float* att_src2 = (const float*)d_in[7];
    const float* att_dst2 = (const float*)d_in[8];
    const float* b2       = (const float*)d_in[9];
    const float* Wl       = (const float*)d_in[10];
    const float* bl       = (const float*)d_in[11];
    float* out = (float*)d_out;

    int N = in_sizes[0] / 3;
    int E = in_sizes[1] / 2;
    const int* src = eidx;
    const int* dst = eidx + E;
    int NBr = (N + BN - 1) / BN;   // 764

    size_t szNHh = (size_t)N * HID * 2;          // 6.4 MB
    size_t szN4  = (size_t)N * 4;
    size_t szPK  = (size_t)NBr * BSTRIDE * 4;    // 14.1 MB

    char* ws = (char*)d_ws;
    __half* h1h    = (__half*)ws; ws += szNHh;
    __half* h2h    = (__half*)ws; ws += szNHh;
    unsigned int* packed = (unsigned int*)ws; ws += szPK;
    float*  a_s1   = (float*)ws;  ws += szN4;
    float*  a_d1   = (float*)ws;  ws += szN4;
    float*  a_s2   = (float*)ws;  ws += szN4;
    float*  a_d2   = (float*)ws;  ws += szN4;
    int*    cursor = (int*)ws;    ws += NBPAD * 4;

    const int B = 256;
    int gridNode32 = (N * HID + B - 1) / B;
    int gridBin    = (E + CHUNK - 1) / CHUNK;

    k_transform1<<<gridNode32, B, 0, stream>>>(x, W1, att_src1, att_dst1,
                                               h1h, a_s1, a_d1, cursor, N);
    k_binscatter<<<gridBin, 512, 0, stream>>>(src, dst, cursor, packed, NBr, E);
    k_agg_mid_f<<<NBr, 512, 0, stream>>>(h1h, a_s1, a_d1, cursor, packed,
                                         b1, W2, att_src2, att_dst2,
                                         h2h, a_s2, a_d2, N);
    k_agg_out_f<<<NBr, 512, 0, stream>>>(h2h, a_s2, a_d2, cursor, packed,
                                         b2, Wl, bl, out, N);
}